// Round 15
// baseline (208.163 us; speedup 1.0000x reference)
//
#include <hip/hip_runtime.h>

// Species-routed expert Linear, R15: IN-BLOCK SPECIES SORT — no gather, no
// scatter, no lists. Block g owns 64 CONSECUTIVE atoms. Wave 0 ballots the
// species ids into a local permutation packing each species into 16-aligned
// MFMA fragments (<=7). rho is read linearly; out written once per row in
// the block's contiguous window; B panels selected per fragment from L2.
//   out[a] = rho[a] @ W[sym[a]] + b[sym[a]]   (NTA=65536, K=N=512, 4 species)

#define NTA   65536
#define DIM_O 512
#define NMAXD 512
#define NSPE  4
#define NSLOT 112            // 16 * 7 max fragments
#define BK    64

typedef __attribute__((ext_vector_type(4))) float  f32x4;
typedef __attribute__((ext_vector_type(8))) short  bf16x8;

__device__ __forceinline__ short f2bf(float f) {
    unsigned u = __builtin_bit_cast(unsigned, f);
    u += 0x7FFFu + ((u >> 16) & 1u);
    return (short)(u >> 16);
}

// Pack W[s][k][n] (fp32) -> bf16 MFMA-B fragment layout (proven R1-R14).
__global__ void pack_w_kernel(const float* __restrict__ W, short* __restrict__ Wp) {
    int idx = blockIdx.x * 256 + threadIdx.x;
    int j  = idx & 7;
    int l  = (idx >> 3) & 63;
    int nb = (idx >> 9) & 31;
    int kb = (idx >> 14) & 15;
    int s  = idx >> 18;
    int k = kb * 32 + (l >> 4) * 8 + j;
    int n = nb * 16 + (l & 15);
    Wp[idx] = f2bf(W[((size_t)s * DIM_O + k) * NMAXD + n]);
}

// LDS A layout (per BK=64 buffer): 16B granule index = c*NSLOT + (slot ^ c),
// c = k-chunk of 8 floats (0..7). XOR makes BOTH the staging write (2 slots x
// 8 c per 16-lane phase) and the fragment read (16 slots x 1 c) 2-way = free.
__global__ __launch_bounds__(512, 2)
void gemm_kernel(const float* __restrict__ rho,
                 const short* __restrict__ Wp,
                 const float* __restrict__ bias,
                 const int*  __restrict__ sym,
                 float* __restrict__ out)
{
    const int g    = blockIdx.x;          // 64 consecutive atoms
    const int tid  = threadIdx.x;
    const int lane = tid & 63;
    const int w    = tid >> 6;            // wave 0..7 owns cols [w*64, w*64+64)
    const int lrow = lane & 15;
    const int lgr  = lane >> 4;

    __shared__ int slotOf[64];
    __shared__ int s2a[NSLOT];
    __shared__ int fspe[8];
    __shared__ int nfrag_sh;
    __shared__ __align__(16) short Ab[2][NSLOT * 8 * 8];   // 2 x 14 KB

    if (tid < NSLOT) s2a[tid] = -1;
    if (tid < 64) {
        const int s = sym[g * 64 + tid];
        const unsigned long long m0 = __ballot(s == 0);
        const unsigned long long m1 = __ballot(s == 1);
        const unsigned long long m2 = __ballot(s == 2);
        const unsigned long long m3 = __ballot(s == 3);
        const int F1 = (__popcll(m0) + 15) >> 4;
        const int F2 = F1 + (int)((__popcll(m1) + 15) >> 4);
        const int F3 = F2 + (int)((__popcll(m2) + 15) >> 4);
        const int F4 = F3 + (int)((__popcll(m3) + 15) >> 4);
        const unsigned long long ms = (s == 0) ? m0 : (s == 1) ? m1 : (s == 2) ? m2 : m3;
        const int Fs = (s == 0) ? 0 : (s == 1) ? F1 : (s == 2) ? F2 : F3;
        const unsigned long long below = (1ull << tid) - 1ull;
        const int slot = Fs * 16 + (int)__popcll(ms & below);
        slotOf[tid] = slot;
        s2a[slot] = tid;
        if (tid < F4) fspe[tid] = (tid >= F1) + (tid >= F2) + (tid >= F3);
        if (tid == 0) nfrag_sh = F4;
    }
    __syncthreads();

    const int nfrag = nfrag_sh;           // block-uniform, 1..7
    int sfr[7];
    #pragma unroll
    for (int f = 0; f < 7; ++f) sfr[f] = (f < nfrag) ? fspe[f] : 0;

    // linear staging: thread t -> natural row t>>3, k-chunk c = t&7;
    // 8 consecutive lanes read 128 B contiguous of one row (requests merge).
    const int c      = tid & 7;
    const int nrow   = tid >> 3;
    const int myslot = slotOf[nrow];
    const int wa16   = c * NSLOT + (myslot ^ c);
    const float* gsrc = rho + ((size_t)(g * 64 + nrow)) * DIM_O + c * 8;

    f32x4 v0, v1;
    v0 = *(const f32x4*)(gsrc);
    v1 = *(const f32x4*)(gsrc + 4);
    {
        bf16x8 pk;
        #pragma unroll
        for (int q = 0; q < 4; ++q) { pk[q] = f2bf(v0[q]); pk[4 + q] = f2bf(v1[q]); }
        *(bf16x8*)&Ab[0][wa16 * 8] = pk;
    }
    __syncthreads();

    f32x4 acc[7][4];
    #pragma unroll
    for (int f = 0; f < 7; ++f)
        #pragma unroll
        for (int n = 0; n < 4; ++n) acc[f][n] = (f32x4)0.0f;

    for (int kt = 0; kt < 8; ++kt) {
        const int buf = kt & 1;
        if (kt < 7) {                      // next K-step's linear loads early
            v0 = *(const f32x4*)(gsrc + (kt + 1) * BK);
            v1 = *(const f32x4*)(gsrc + (kt + 1) * BK + 4);
        }
        #pragma unroll
        for (int ks = 0; ks < 2; ++ks) {
            const int cA = ks * 4 + lgr;
            #pragma unroll
            for (int f = 0; f < 7; ++f) {
                if (f < nfrag) {           // block-uniform
                    const short* wb = Wp + ((size_t)sfr[f] * 512 + w * 4) * 512 + lane * 8;
                    bf16x8 bfr[4];
                    #pragma unroll
                    for (int nf = 0; nf < 4; ++nf)
                        bfr[nf] = *(const bf16x8*)
                            (wb + (size_t)((kt * 2 + ks) * 32 + nf) * 512);
                    const bf16x8 af =
                        *(const bf16x8*)&Ab[buf][(cA * NSLOT + ((16 * f + lrow) ^ cA)) * 8];
                    #pragma unroll
                    for (int nf = 0; nf < 4; ++nf)
                        acc[f][nf] = __builtin_amdgcn_mfma_f32_16x16x32_bf16(
                            af, bfr[nf], acc[f][nf], 0, 0, 0);
                }
            }
        }
        if (kt < 7) {
            bf16x8 pk;
            #pragma unroll
            for (int q = 0; q < 4; ++q) { pk[q] = f2bf(v0[q]); pk[4 + q] = f2bf(v1[q]); }
            *(bf16x8*)&Ab[buf ^ 1][wa16 * 8] = pk;
            __syncthreads();
        }
    }

    // epilogue: per-fragment bias + store; every atom row written exactly once
    // into the block's contiguous 128 KB window.
    #pragma unroll
    for (int f = 0; f < 7; ++f) {
        if (f < nfrag) {
            const int sp = sfr[f];
            float bv[4];
            #pragma unroll
            for (int nf = 0; nf < 4; ++nf)
                bv[nf] = bias[sp * NMAXD + w * 64 + nf * 16 + lrow];
            #pragma unroll
            for (int q = 0; q < 4; ++q) {
                const int atom = s2a[16 * f + lgr * 4 + q];
                if (atom >= 0) {
                    float* orow = out + ((size_t)(g * 64 + atom)) * NMAXD + w * 64 + lrow;
                    #pragma unroll
                    for (int nf = 0; nf < 4; ++nf)
                        orow[nf * 16] = acc[f][nf][q] + bv[nf];
                }
            }
        }
    }
}

extern "C" void kernel_launch(void* const* d_in, const int* in_sizes, int n_in,
                              void* d_out, int out_size, void* d_ws, size_t ws_size,
                              hipStream_t stream) {
    const float* rho = (const float*)d_in[0];
    const float* W   = (const float*)d_in[1];
    const float* b   = (const float*)d_in[2];
    const int*   sym = (const int*)d_in[3];
    float* out = (float*)d_out;

    short* Wp = (short*)d_ws;   // 2 MB

    pack_w_kernel<<<(NSPE * DIM_O * NMAXD) / 256, 256, 0, stream>>>(W, Wp);
    gemm_kernel<<<NTA / 64, 512, 0, stream>>>(rho, Wp, b, sym, out);
}